// Round 1
// baseline (97.034 us; speedup 1.0000x reference)
//
#include <hip/hip_runtime.h>

#define NB 8
#define NC 3
#define NQ 4096   // h*w = 64*64
#define NP 2048

// Main fused kernel.
//  blocks [0,256):   bp direction. blk -> b = blk>>5, pb = (blk>>2)&7, qc = blk&3
//                    block stages y-chunk (1024 q) in LDS, each thread owns one p,
//                    writes part_bp[b][p][qc] = min over its q-chunk.
//  blocks [256,512): bq direction. idx = blk-256 -> b = idx>>5, qb = (idx>>1)&15, pc = idx&1
//                    block stages t-chunk (1024 p) in LDS, each thread owns one q,
//                    writes part_bq[b][q][pc] = min over its p-chunk.
__global__ __launch_bounds__(256) void chamfer_main(const float* __restrict__ y,
                                                    const float* __restrict__ t,
                                                    const float* __restrict__ w,
                                                    float* __restrict__ part_bp,  // [NB][NP][4]
                                                    float* __restrict__ part_bq)  // [NB][NQ][2]
{
    __shared__ float4 lds[1024];
    const int tid = threadIdx.x;
    const float w0 = w[0] * w[0];
    const float w1 = w[1] * w[1];
    const float w2 = w[2] * w[2];
    const int blk = blockIdx.x;

    if (blk < 256) {
        // ---- bp direction ----
        const int b  = blk >> 5;
        const int pb = (blk >> 2) & 7;
        const int qc = blk & 3;
        const float* yb = y + (size_t)b * NC * NQ;
        for (int i = tid; i < 1024; i += 256) {
            const int q = qc * 1024 + i;
            const float y0 = yb[q];
            const float y1 = yb[NQ + q];
            const float y2 = yb[2 * NQ + q];
            const float wy2 = w0 * y0 * y0 + w1 * y1 * y1 + w2 * y2 * y2;
            lds[i] = make_float4(y0, y1, y2, wy2);
        }
        __syncthreads();

        const int p = pb * 256 + tid;
        const float* tp = t + ((size_t)b * NP + p) * NC;
        const float t0 = tp[0], t1 = tp[1], t2 = tp[2];
        const float a0 = 2.0f * w0 * t0;
        const float a1 = 2.0f * w1 * t1;
        const float a2 = 2.0f * w2 * t2;
        const float wt2 = w0 * t0 * t0 + w1 * t1 * t1 + w2 * t2 * t2;

        float m = 3.4e38f;
        #pragma unroll 8
        for (int i = 0; i < 1024; ++i) {
            const float4 v = lds[i];
            const float d = (wt2 + v.w) - (a0 * v.x + a1 * v.y + a2 * v.z);
            m = fminf(m, d);
        }
        part_bp[((size_t)b * NP + p) * 4 + qc] = m;
    } else {
        // ---- bq direction ----
        const int idx = blk - 256;
        const int b  = idx >> 5;
        const int qb = (idx >> 1) & 15;
        const int pc = idx & 1;
        const float* tb = t + (size_t)b * NP * NC;
        for (int i = tid; i < 1024; i += 256) {
            const int p = pc * 1024 + i;
            const float t0 = tb[p * 3 + 0];
            const float t1 = tb[p * 3 + 1];
            const float t2 = tb[p * 3 + 2];
            const float wt2 = w0 * t0 * t0 + w1 * t1 * t1 + w2 * t2 * t2;
            lds[i] = make_float4(t0, t1, t2, wt2);
        }
        __syncthreads();

        const int q = qb * 256 + tid;
        const float* yb = y + (size_t)b * NC * NQ;
        const float y0 = yb[q];
        const float y1 = yb[NQ + q];
        const float y2 = yb[2 * NQ + q];
        const float b0 = 2.0f * w0 * y0;
        const float b1 = 2.0f * w1 * y1;
        const float b2 = 2.0f * w2 * y2;
        const float wy2 = w0 * y0 * y0 + w1 * y1 * y1 + w2 * y2 * y2;

        float m = 3.4e38f;
        #pragma unroll 8
        for (int i = 0; i < 1024; ++i) {
            const float4 v = lds[i];
            const float d = (wy2 + v.w) - (b0 * v.x + b1 * v.y + b2 * v.z);
            m = fminf(m, d);
        }
        part_bq[((size_t)b * NQ + q) * 2 + pc] = m;
    }
}

// Single-block deterministic reduce: min over chunk partials, two means, sum.
__global__ __launch_bounds__(1024) void chamfer_reduce(const float4* __restrict__ part_bp4, // [NB*NP]
                                                       const float2* __restrict__ part_bq2, // [NB*NQ]
                                                       float* __restrict__ out)
{
    const int tid = threadIdx.x;
    double sbp = 0.0, sbq = 0.0;
    for (int i = tid; i < NB * NP; i += 1024) {
        const float4 v = part_bp4[i];
        sbp += (double)fminf(fminf(v.x, v.y), fminf(v.z, v.w));
    }
    for (int i = tid; i < NB * NQ; i += 1024) {
        const float2 v = part_bq2[i];
        sbq += (double)fminf(v.x, v.y);
    }
    double s = sbp * (1.0 / (NB * NP)) + sbq * (1.0 / (NB * NQ));

    // wave reduce (64 lanes)
    for (int off = 32; off > 0; off >>= 1) s += __shfl_down(s, off);

    __shared__ double red[16];
    const int wave = tid >> 6;
    const int lane = tid & 63;
    if (lane == 0) red[wave] = s;
    __syncthreads();
    if (tid == 0) {
        double tot = 0.0;
        for (int i = 0; i < 16; ++i) tot += red[i];
        out[0] = (float)tot;
    }
}

extern "C" void kernel_launch(void* const* d_in, const int* in_sizes, int n_in,
                              void* d_out, int out_size, void* d_ws, size_t ws_size,
                              hipStream_t stream) {
    const float* y = (const float*)d_in[0];   // [8,3,64,64]
    const float* t = (const float*)d_in[1];   // [8,2048,3]
    const float* w = (const float*)d_in[2];   // [3]
    float* out = (float*)d_out;

    float* part_bp = (float*)d_ws;                       // NB*NP*4 floats = 256 KB
    float* part_bq = part_bp + (size_t)NB * NP * 4;      // NB*NQ*2 floats = 256 KB

    chamfer_main<<<512, 256, 0, stream>>>(y, t, w, part_bp, part_bq);
    chamfer_reduce<<<1, 1024, 0, stream>>>((const float4*)part_bp,
                                           (const float2*)part_bq, out);
}

// Round 2
// 27.559 us; speedup vs baseline: 3.5209x; 3.5209x over previous
//
#include <hip/hip_runtime.h>

#define NB 8
#define NQ 4096   // h*w
#define NP 2048
#define FINF 3.402823466e38f

// Main fused kernel, 512 blocks x 256 threads.
//  blocks [0,256):   bp. blk -> b=blk>>5, pb=(blk>>2)&7 (owns 256 p), qc=blk&3 (stages 1024 q).
//  blocks [256,512): bq. idx -> b=idx>>5, qb=(idx>>1)&15 (owns 256 q), pc=idx&1 (stages 1024 p).
// Thread decomposition: pg = tid&31 owns 8 points (p_local = pg*8+r); s = tid>>5 takes a
// 128-entry slice of the staged 1024 points. Epilogue: LDS min-reduce over the 8 s-slices.
// Partials: part_bp [4][NB][NP], part_bq [2][NB][NQ]  (chunk-major planes, coalesced writes).
__global__ __launch_bounds__(256) void chamfer_main(const float* __restrict__ y,
                                                    const float* __restrict__ t,
                                                    const float* __restrict__ w,
                                                    float* __restrict__ part_bp,
                                                    float* __restrict__ part_bq)
{
    __shared__ float4 ldsPts[1024];   // staged points: (c0,c1,c2, wnorm2)
    __shared__ float4 ldsQuad[256];   // owned points: (-2w2*c0,-2w2*c1,-2w2*c2, wnorm2)
    __shared__ float  red[2048];      // s-slice reduction

    const int tid = threadIdx.x;
    const int pg  = tid & 31;
    const int s   = tid >> 5;
    const float w0 = w[0]*w[0], w1 = w[1]*w[1], w2 = w[2]*w[2];
    const int blk = blockIdx.x;

    float* out_ptr;
    size_t out_idx;

    if (blk < 256) {
        // ---- bp: own p, stage y(q) ----
        const int b   = blk >> 5;
        const int rem = blk & 31;
        const int pb  = rem >> 2;
        const int qc  = rem & 3;
        const float* yb = y + (size_t)b * 3 * NQ;
        for (int i = tid; i < 1024; i += 256) {
            const int q = qc * 1024 + i;
            const float y0 = yb[q], y1 = yb[NQ + q], y2 = yb[2*NQ + q];
            ldsPts[i] = make_float4(y0, y1, y2, w0*y0*y0 + w1*y1*y1 + w2*y2*y2);
        }
        {
            const int p = pb * 256 + tid;
            const float* tp = t + ((size_t)b * NP + p) * 3;
            const float t0 = tp[0], t1 = tp[1], t2 = tp[2];
            ldsQuad[tid] = make_float4(-2.f*w0*t0, -2.f*w1*t1, -2.f*w2*t2,
                                       w0*t0*t0 + w1*t1*t1 + w2*t2*t2);
        }
        out_ptr = part_bp;
        out_idx = (size_t)qc * (NB * NP) + (size_t)b * NP + pb * 256;
    } else {
        // ---- bq: own q, stage t(p) ----
        const int idx = blk - 256;
        const int b   = idx >> 5;
        const int rem = idx & 31;
        const int qb  = rem >> 1;
        const int pc  = rem & 1;
        const float* tb = t + (size_t)b * NP * 3;
        for (int i = tid; i < 1024; i += 256) {
            const int p = pc * 1024 + i;
            const float t0 = tb[p*3 + 0], t1 = tb[p*3 + 1], t2 = tb[p*3 + 2];
            ldsPts[i] = make_float4(t0, t1, t2, w0*t0*t0 + w1*t1*t1 + w2*t2*t2);
        }
        {
            const int q = qb * 256 + tid;
            const float* yb = y + (size_t)b * 3 * NQ;
            const float y0 = yb[q], y1 = yb[NQ + q], y2 = yb[2*NQ + q];
            ldsQuad[tid] = make_float4(-2.f*w0*y0, -2.f*w1*y1, -2.f*w2*y2,
                                       w0*y0*y0 + w1*y1*y1 + w2*y2*y2);
        }
        out_ptr = part_bq;
        out_idx = (size_t)pc * (NB * NQ) + (size_t)b * NQ + qb * 256;
    }
    __syncthreads();

    float4 qd[8];
    float  mm[8];
    #pragma unroll
    for (int r = 0; r < 8; ++r) { qd[r] = ldsQuad[pg*8 + r]; mm[r] = FINF; }

    const float4* myLds = ldsPts + s * 128;
    #pragma unroll 4
    for (int i = 0; i < 128; ++i) {
        const float4 v = myLds[i];
        #pragma unroll
        for (int r = 0; r < 8; ++r) {
            float acc = v.w + qd[r].w;          // wnorm2_staged + wnorm2_owned
            acc = fmaf(qd[r].x, v.x, acc);      // - 2 w^2 c0 * c0'
            acc = fmaf(qd[r].y, v.y, acc);
            acc = fmaf(qd[r].z, v.z, acc);
            mm[r] = fminf(mm[r], acc);
        }
    }

    // reduce the 8 s-slices per owned point
    float4* r4 = (float4*)red;
    r4[s*64 + pg*2 + 0] = make_float4(mm[0], mm[1], mm[2], mm[3]);
    r4[s*64 + pg*2 + 1] = make_float4(mm[4], mm[5], mm[6], mm[7]);
    __syncthreads();

    float v = red[tid];
    #pragma unroll
    for (int s2 = 1; s2 < 8; ++s2) v = fminf(v, red[s2*256 + tid]);
    out_ptr[out_idx + tid] = v;
}

// Single-block deterministic reduce: min over chunk planes, two means, sum.
__global__ __launch_bounds__(1024) void chamfer_reduce(const float4* __restrict__ bp4, // [4][4096]
                                                       const float4* __restrict__ bq4, // [2][8192]
                                                       float* __restrict__ out)
{
    const int tid = threadIdx.x;
    double sbp = 0.0, sbq = 0.0;
    for (int i = tid; i < 4096; i += 1024) {
        const float4 a = bp4[i], b = bp4[4096 + i], c = bp4[2*4096 + i], d = bp4[3*4096 + i];
        sbp += (double)fminf(fminf(a.x, b.x), fminf(c.x, d.x));
        sbp += (double)fminf(fminf(a.y, b.y), fminf(c.y, d.y));
        sbp += (double)fminf(fminf(a.z, b.z), fminf(c.z, d.z));
        sbp += (double)fminf(fminf(a.w, b.w), fminf(c.w, d.w));
    }
    for (int i = tid; i < 8192; i += 1024) {
        const float4 a = bq4[i], b = bq4[8192 + i];
        sbq += (double)fminf(a.x, b.x);
        sbq += (double)fminf(a.y, b.y);
        sbq += (double)fminf(a.z, b.z);
        sbq += (double)fminf(a.w, b.w);
    }
    double sv = sbp * (1.0 / (NB * NP)) + sbq * (1.0 / (NB * NQ));

    for (int off = 32; off > 0; off >>= 1) sv += __shfl_down(sv, off);

    __shared__ double redd[16];
    const int wave = tid >> 6;
    const int lane = tid & 63;
    if (lane == 0) redd[wave] = sv;
    __syncthreads();
    if (tid == 0) {
        double tot = 0.0;
        for (int i = 0; i < 16; ++i) tot += redd[i];
        out[0] = (float)tot;
    }
}

extern "C" void kernel_launch(void* const* d_in, const int* in_sizes, int n_in,
                              void* d_out, int out_size, void* d_ws, size_t ws_size,
                              hipStream_t stream) {
    const float* y = (const float*)d_in[0];   // [8,3,64,64]
    const float* t = (const float*)d_in[1];   // [8,2048,3]
    const float* w = (const float*)d_in[2];   // [3]
    float* out = (float*)d_out;

    float* part_bp = (float*)d_ws;                       // 4*NB*NP floats = 256 KB
    float* part_bq = part_bp + (size_t)4 * NB * NP;      // 2*NB*NQ floats = 256 KB

    chamfer_main<<<512, 256, 0, stream>>>(y, t, w, part_bp, part_bq);
    chamfer_reduce<<<1, 1024, 0, stream>>>((const float4*)part_bp,
                                           (const float2*)part_bq ? (const float4*)part_bq : nullptr,
                                           out);
}

// Round 3
// 24.721 us; speedup vs baseline: 3.9252x; 1.1148x over previous
//
#include <hip/hip_runtime.h>

#define NB 8
#define NQ 4096   // h*w
#define NP 2048
#define FINF 3.402823466e38f

// Main kernel: 768 blocks x 256 threads.
//  blocks [0,256):   bp. b = blk>>5, pb = blk&31 -> owns 64 p's; stages ALL 4096 y-pts (64KB).
//  blocks [256,768): bq. idx=blk-256, b = idx>>6, qb = idx&63 -> owns 64 q's; stages ALL 2048 t-pts.
// Thread split: pg = tid&3 owns 16 points (reg tile), s = tid>>2 in [0,64) takes a slice of the
// staged points. Epilogue: min-reduce over 64 s-slices (scratch reuses ldsPts), add deferred
// owned-norm, then deterministic wave-sum of the 64 complete mins -> blockSums[blk] (1 float).
__global__ __launch_bounds__(256) void chamfer_main(const float* __restrict__ y,
                                                    const float* __restrict__ t,
                                                    const float* __restrict__ w,
                                                    float* __restrict__ blockSums)
{
    __shared__ float4 ldsPts[4096];   // staged points (c0,c1,c2, wnorm2); scratch after reuse
    __shared__ float4 ldsQuad[64];    // owned points (-2w2c0,-2w2c1,-2w2c2, wnorm2)

    const int tid = threadIdx.x;
    const int pg  = tid & 3;     // owned-point group (16 each)
    const int s   = tid >> 2;    // staged-slice index [0,64)
    const float w0 = w[0]*w[0], w1 = w[1]*w[1], w2 = w[2]*w[2];
    const int blk = blockIdx.x;

    int nStage;  // staged points this block

    if (blk < 256) {
        // ---- bp: own 64 p, stage 4096 y ----
        const int b  = blk >> 5;
        const int pb = blk & 31;
        const float* yb = y + (size_t)b * 3 * NQ;
        for (int i = tid; i < NQ; i += 256) {
            const float y0 = yb[i], y1 = yb[NQ + i], y2 = yb[2*NQ + i];
            ldsPts[i] = make_float4(y0, y1, y2, w0*y0*y0 + w1*y1*y1 + w2*y2*y2);
        }
        if (tid < 64) {
            const int p = pb * 64 + tid;
            const float* tp = t + ((size_t)b * NP + p) * 3;
            const float t0 = tp[0], t1 = tp[1], t2 = tp[2];
            ldsQuad[tid] = make_float4(-2.f*w0*t0, -2.f*w1*t1, -2.f*w2*t2,
                                       w0*t0*t0 + w1*t1*t1 + w2*t2*t2);
        }
        nStage = NQ;
    } else {
        // ---- bq: own 64 q, stage 2048 t ----
        const int idx = blk - 256;
        const int b   = idx >> 6;
        const int qb  = idx & 63;
        const float* tb = t + (size_t)b * NP * 3;
        for (int i = tid; i < NP; i += 256) {
            const float t0 = tb[i*3 + 0], t1 = tb[i*3 + 1], t2 = tb[i*3 + 2];
            ldsPts[i] = make_float4(t0, t1, t2, w0*t0*t0 + w1*t1*t1 + w2*t2*t2);
        }
        if (tid < 64) {
            const int q = qb * 64 + tid;
            const float* yb = y + (size_t)b * 3 * NQ;
            const float y0 = yb[q], y1 = yb[NQ + q], y2 = yb[2*NQ + q];
            ldsQuad[tid] = make_float4(-2.f*w0*y0, -2.f*w1*y1, -2.f*w2*y2,
                                       w0*y0*y0 + w1*y1*y1 + w2*y2*y2);
        }
        nStage = NP;
    }
    __syncthreads();

    float4 qd[16];
    float  mm[16];
    #pragma unroll
    for (int r = 0; r < 16; ++r) { qd[r] = ldsQuad[pg*16 + r]; mm[r] = FINF; }

    const int sliceLen = nStage >> 6;            // 64 (bp) or 32 (bq)
    const float4* myLds = ldsPts + s * sliceLen;
    #pragma unroll 2
    for (int i = 0; i < sliceLen; ++i) {
        const float4 v = myLds[i];
        #pragma unroll
        for (int r = 0; r < 16; ++r) {
            float acc = fmaf(qd[r].x, v.x, v.w);   // staged_norm - 2w^2 * dot
            acc = fmaf(qd[r].y, v.y, acc);
            acc = fmaf(qd[r].z, v.z, acc);
            mm[r] = fminf(mm[r], acc);             // owned norm deferred to epilogue
        }
    }
    __syncthreads();   // all ldsPts reads done -> reuse as scratch

    // scratch layout: scr[s][j] = partial min of owned point j over slice s (64x64)
    float* scr = (float*)ldsPts;            // 4096 floats
    float* scrB = scr + 4096;               // 256 floats (stage-1 output)
    #pragma unroll
    for (int r = 0; r < 16; ++r) scr[s*64 + pg*16 + r] = mm[r];
    __syncthreads();

    // stage 1: 256 threads, each folds 16 s-slices for one owned point
    {
        const int j  = tid & 63;
        const int s0 = tid >> 6;            // [0,4)
        float v = scr[(s0*16 + 0)*64 + j];
        #pragma unroll
        for (int k = 1; k < 16; ++k) v = fminf(v, scr[(s0*16 + k)*64 + j]);
        scrB[s0*64 + j] = v;
    }
    __syncthreads();

    // stage 2: wave 0 finishes min, adds deferred owned norm, sums 64 values
    if (tid < 64) {
        float v = fminf(fminf(scrB[tid], scrB[64 + tid]),
                        fminf(scrB[128 + tid], scrB[192 + tid]));
        v += ldsQuad[tid].w;
        for (int off = 32; off > 0; off >>= 1) v += __shfl_down(v, off);
        if (tid == 0) blockSums[blk] = v;
    }
}

// Final: single block, deterministic. bp sums in blockSums[0..256), bq in [256..768).
__global__ __launch_bounds__(256) void chamfer_final(const float* __restrict__ blockSums,
                                                     float* __restrict__ out)
{
    const int tid = threadIdx.x;
    double sv = (double)blockSums[tid] * (1.0 / (NB * NP))
              + ((double)blockSums[256 + tid] + (double)blockSums[512 + tid]) * (1.0 / (NB * NQ));

    for (int off = 32; off > 0; off >>= 1) sv += __shfl_down(sv, off);

    __shared__ double redd[4];
    const int wave = tid >> 6;
    const int lane = tid & 63;
    if (lane == 0) redd[wave] = sv;
    __syncthreads();
    if (tid == 0) out[0] = (float)(redd[0] + redd[1] + redd[2] + redd[3]);
}

extern "C" void kernel_launch(void* const* d_in, const int* in_sizes, int n_in,
                              void* d_out, int out_size, void* d_ws, size_t ws_size,
                              hipStream_t stream) {
    const float* y = (const float*)d_in[0];   // [8,3,64,64]
    const float* t = (const float*)d_in[1];   // [8,2048,3]
    const float* w = (const float*)d_in[2];   // [3]
    float* out = (float*)d_out;

    float* blockSums = (float*)d_ws;          // 768 floats

    chamfer_main<<<768, 256, 0, stream>>>(y, t, w, blockSums);
    chamfer_final<<<1, 256, 0, stream>>>(blockSums, out);
}

// Round 4
// 20.453 us; speedup vs baseline: 4.7442x; 1.2086x over previous
//
#include <hip/hip_runtime.h>

#define NB 8
#define NQ 4096   // h*w
#define NP 2048
#define FINF 3.402823466e38f

typedef float f2 __attribute__((ext_vector_type(2)));
typedef float f4 __attribute__((ext_vector_type(4)));

__device__ __forceinline__ f2 pk_fma(f2 a, f2 b, f2 c) {
    f2 d;
    asm("v_pk_fma_f32 %0, %1, %2, %3" : "=v"(d) : "v"(a), "v"(b), "v"(c));
    return d;
}
__device__ __forceinline__ float min3f(float a, float b, float c) {
    float d;
    asm("v_min3_f32 %0, %1, %2, %3" : "=v"(d) : "v"(a), "v"(b), "v"(c));
    return d;
}

// 512 blocks x 256 threads, exactly 2 blocks/CU (66 KB LDS), uniform work.
//  blocks [0,256):   bp. b=blk>>5, pb=blk&31: owns 64 p; stages all 4096 y as 2048 pairs.
//  blocks [256,512): bq. b=idx>>5, qb=idx&31: owns 128 q; stages all 2048 t as 1024 pairs.
// Pair j in LDS: A[j]=(x0,x1,y0,y1), B[j]=(z0,z1,n0,n1) with n = w^2-norm of the point.
// Thread split: pg owns 16 points (reg-resident, broadcast pairs), s is the slice index.
// Slice access is INTERLEAVED (pair = j*nSlices + s) so a wave's lanes hit consecutive
// 16B LDS slots -> conflict-free ds_read_b128. Inner 2-distance step: 3 v_pk_fma_f32 +
// 1 v_min3_f32 (owned norm deferred to epilogue). Per block -> 1 float partial sum.
__global__ __launch_bounds__(256) void chamfer_main(const float* __restrict__ y,
                                                    const float* __restrict__ t,
                                                    const float* __restrict__ w,
                                                    float* __restrict__ blockSums)
{
    __shared__ f4 ldsA[2048];   // 32 KB
    __shared__ f4 ldsB[2048];   // 32 KB
    __shared__ f4 ldsQuad[128]; // owned: (-2w2c0, -2w2c1, -2w2c2, norm)
    __shared__ float wsum[2];

    const int tid = threadIdx.x;
    const int blk = blockIdx.x;
    const float w0 = w[0]*w[0], w1 = w[1]*w[1], w2 = w[2]*w[2];

    int nOwn, nSlices, pg, s;

    if (blk < 256) {
        // ---- bp: own 64 p, stage 4096 y-points (2048 pairs) ----
        nOwn = 64; nSlices = 64; pg = tid & 3; s = tid >> 2;
        const int b = blk >> 5, pb = blk & 31;
        const float* yb = y + (size_t)b * 3 * NQ;
        const f2* xs = (const f2*)yb;
        const f2* ys = (const f2*)(yb + NQ);
        const f2* zs = (const f2*)(yb + 2*NQ);
        for (int i = tid; i < 2048; i += 256) {
            const f2 xp = xs[i], yp = ys[i], zp = zs[i];
            const float n0 = w0*xp.x*xp.x + w1*yp.x*yp.x + w2*zp.x*zp.x;
            const float n1 = w0*xp.y*xp.y + w1*yp.y*yp.y + w2*zp.y*zp.y;
            f4 va = {xp.x, xp.y, yp.x, yp.y};
            f4 vb = {zp.x, zp.y, n0, n1};
            ldsA[i] = va; ldsB[i] = vb;
        }
        if (tid < 64) {
            const float* tp = t + ((size_t)b * NP + pb*64 + tid) * 3;
            const float t0 = tp[0], t1 = tp[1], t2 = tp[2];
            f4 q = {-2.f*w0*t0, -2.f*w1*t1, -2.f*w2*t2,
                    w0*t0*t0 + w1*t1*t1 + w2*t2*t2};
            ldsQuad[tid] = q;
        }
    } else {
        // ---- bq: own 128 q, stage 2048 t-points (1024 pairs) ----
        nOwn = 128; nSlices = 32; pg = tid & 7; s = tid >> 3;
        const int idx = blk - 256;
        const int b = idx >> 5, qb = idx & 31;
        const float* tb = t + (size_t)b * NP * 3;
        for (int i = tid; i < 1024; i += 256) {
            const f2* tp2 = (const f2*)(tb + i*6);
            const f2 u0 = tp2[0], u1 = tp2[1], u2 = tp2[2];
            // pt0=(u0.x,u0.y,u1.x)  pt1=(u1.y,u2.x,u2.y)
            const float n0 = w0*u0.x*u0.x + w1*u0.y*u0.y + w2*u1.x*u1.x;
            const float n1 = w0*u1.y*u1.y + w1*u2.x*u2.x + w2*u2.y*u2.y;
            f4 va = {u0.x, u1.y, u0.y, u2.x};
            f4 vb = {u1.x, u2.y, n0, n1};
            ldsA[i] = va; ldsB[i] = vb;
        }
        if (tid < 128) {
            const float* yb = y + (size_t)b * 3 * NQ;
            const int q = qb*128 + tid;
            const float y0 = yb[q], y1 = yb[NQ+q], y2 = yb[2*NQ+q];
            f4 qv = {-2.f*w0*y0, -2.f*w1*y1, -2.f*w2*y2,
                     w0*y0*y0 + w1*y1*y1 + w2*y2*y2};
            ldsQuad[tid] = qv;
        }
    }
    __syncthreads();

    // hoist owned points into broadcast register pairs
    const int j0 = pg * 16;
    f2 qx[16], qy[16], qz[16];
    float mm[16];
    #pragma unroll
    for (int r = 0; r < 16; ++r) {
        const f4 qv = ldsQuad[j0 + r];
        f2 bx = {qv.x, qv.x}; qx[r] = bx;
        f2 by = {qv.y, qv.y}; qy[r] = by;
        f2 bz = {qv.z, qv.z}; qz[r] = bz;
        mm[r] = FINF;
    }

    // 32 interleaved pair-steps = 64 staged points per thread
    const f4* Ap = ldsA + s;
    const f4* Bp = ldsB + s;
    #pragma unroll 4
    for (int j = 0; j < 32; ++j) {
        const f4 a  = Ap[j * nSlices];
        const f4 bb = Bp[j * nSlices];
        const f2 vx = a.xy,  vy = a.zw;
        const f2 vz = bb.xy, vn = bb.zw;
        #pragma unroll
        for (int r = 0; r < 16; ++r) {
            f2 acc = pk_fma(qx[r], vx, vn);
            acc = pk_fma(qy[r], vy, acc);
            acc = pk_fma(qz[r], vz, acc);
            mm[r] = min3f(mm[r], acc.x, acc.y);
        }
    }
    __syncthreads();   // done reading ldsA/ldsB -> reuse as scratch

    // scr[j_own * (S+1) + s]  (padded stride -> conflict-free)
    float* scr = (float*)ldsA;
    const int SP1 = nSlices + 1;
    #pragma unroll
    for (int r = 0; r < 16; ++r) scr[(j0 + r) * SP1 + s] = mm[r];
    __syncthreads();

    // stage 1: each thread folds 16 slices of one owned point
    float* scrB = (float*)ldsB;
    {
        const int j  = tid & (nOwn - 1);
        const int s0 = tid / nOwn;              // [0, 256/nOwn)
        float v = FINF;
        #pragma unroll
        for (int k = 0; k < 16; ++k) v = fminf(v, scr[j * SP1 + s0*16 + k]);
        scrB[s0 * nOwn + j] = v;
    }
    __syncthreads();

    // stage 2: finish min, add deferred owned norm, sum owned points
    if (tid < nOwn) {
        const int nG = 256 / nOwn;
        float v = scrB[tid];
        for (int g = 1; g < nG; ++g) v = fminf(v, scrB[g * nOwn + tid]);
        v += ldsQuad[tid].w;
        for (int off = 32; off > 0; off >>= 1) v += __shfl_down(v, off);
        if ((tid & 63) == 0) wsum[tid >> 6] = v;
    }
    __syncthreads();
    if (tid == 0) blockSums[blk] = (nOwn == 128) ? (wsum[0] + wsum[1]) : wsum[0];
}

// Final: single block, deterministic. bp sums in [0,256), bq sums in [256,512).
__global__ __launch_bounds__(256) void chamfer_final(const float* __restrict__ bs,
                                                     float* __restrict__ out)
{
    const int tid = threadIdx.x;
    double sv = (double)bs[tid] * (1.0 / (NB * NP))
              + (double)bs[256 + tid] * (1.0 / (NB * NQ));
    for (int off = 32; off > 0; off >>= 1) sv += __shfl_down(sv, off);
    __shared__ double redd[4];
    if ((tid & 63) == 0) redd[tid >> 6] = sv;
    __syncthreads();
    if (tid == 0) out[0] = (float)(redd[0] + redd[1] + redd[2] + redd[3]);
}

extern "C" void kernel_launch(void* const* d_in, const int* in_sizes, int n_in,
                              void* d_out, int out_size, void* d_ws, size_t ws_size,
                              hipStream_t stream) {
    const float* y = (const float*)d_in[0];   // [8,3,64,64]
    const float* t = (const float*)d_in[1];   // [8,2048,3]
    const float* w = (const float*)d_in[2];   // [3]
    float* out = (float*)d_out;

    float* blockSums = (float*)d_ws;          // 512 floats

    chamfer_main<<<512, 256, 0, stream>>>(y, t, w, blockSums);
    chamfer_final<<<1, 256, 0, stream>>>(blockSums, out);
}